// Round 1
// baseline (2287.147 us; speedup 1.0000x reference)
//
#include <hip/hip_runtime.h>
#include <math.h>

// ---------------------------------------------------------------------------
// Types / helpers
// ---------------------------------------------------------------------------
typedef __bf16 bf16x8 __attribute__((ext_vector_type(8)));
typedef float floatx4 __attribute__((ext_vector_type(4)));

__device__ __forceinline__ unsigned short f32_to_bf16(float f) {
  unsigned int u = __float_as_uint(f);
  u = u + 0x7FFFu + ((u >> 16) & 1u);   // RNE; inputs finite so no NaN handling
  return (unsigned short)(u >> 16);
}
__device__ __forceinline__ float bf16_to_f32(unsigned short s) {
  return __uint_as_float(((unsigned int)s) << 16);
}

// ---------------------------------------------------------------------------
// fp32 -> bf16 cast (vectorized float4 -> ushort4)
// ---------------------------------------------------------------------------
__global__ void cast_kernel(const float* __restrict__ in,
                            unsigned short* __restrict__ out, int n4) {
  int i = blockIdx.x * blockDim.x + threadIdx.x;
  if (i >= n4) return;
  const float4 v = reinterpret_cast<const float4*>(in)[i];
  ushort4 o;
  o.x = f32_to_bf16(v.x); o.y = f32_to_bf16(v.y);
  o.z = f32_to_bf16(v.z); o.w = f32_to_bf16(v.w);
  reinterpret_cast<ushort4*>(out)[i] = o;
}

// ---------------------------------------------------------------------------
// GEMM: C[m][n] = sum_k A[m][k]*B[n][k] + bias[n]
// A: MxK bf16 row-major, B: NxK bf16 row-major ("B^T" GEMM), C: MxN fp32.
// 128x128 tile, BK=64, 4 waves, each wave 64x64 via 4x4 of 16x16x32 MFMA.
// LDS stride 72 bf16 (=144B): b128 frag reads start at 8 distinct bank groups.
// ---------------------------------------------------------------------------
constexpr int GT_M = 128, GT_N = 128, GT_K = 64;
constexpr int GLDA = GT_K + 8;  // 72 elements

__global__ __launch_bounds__(256) void gemm_bt_bias(
    const unsigned short* __restrict__ A, const unsigned short* __restrict__ B,
    const float* __restrict__ bias, float* __restrict__ C,
    int M, int N, int K) {
  __shared__ unsigned short As[GT_M * GLDA];
  __shared__ unsigned short Bs[GT_N * GLDA];
  const int t = threadIdx.x;
  const int lane = t & 63;
  const int wave = t >> 6;
  const int bm = blockIdx.y * GT_M;
  const int bn = blockIdx.x * GT_N;
  const int wm = (wave & 1) * 64;
  const int wn = (wave >> 1) * 64;
  const int m16 = lane & 15;
  const int quad = lane >> 4;

  floatx4 acc[4][4];
#pragma unroll
  for (int i = 0; i < 4; ++i)
#pragma unroll
    for (int j = 0; j < 4; ++j) acc[i][j] = floatx4{0.f, 0.f, 0.f, 0.f};

  const int row0 = t >> 3;        // 0..31 (8 threads per row)
  const int col8 = (t & 7) * 8;   // 0..56 (element offset, 16B chunks)

  for (int k0 = 0; k0 < K; k0 += GT_K) {
    const unsigned short* Ag = A + (size_t)(bm + row0) * K + k0 + col8;
    const unsigned short* Bg = B + (size_t)(bn + row0) * K + k0 + col8;
#pragma unroll
    for (int it = 0; it < 4; ++it) {
      *reinterpret_cast<uint4*>(&As[(row0 + it * 32) * GLDA + col8]) =
          *reinterpret_cast<const uint4*>(Ag + (size_t)it * 32 * K);
      *reinterpret_cast<uint4*>(&Bs[(row0 + it * 32) * GLDA + col8]) =
          *reinterpret_cast<const uint4*>(Bg + (size_t)it * 32 * K);
    }
    __syncthreads();
#pragma unroll
    for (int ks = 0; ks < GT_K; ks += 32) {
      bf16x8 af[4], bfr[4];
#pragma unroll
      for (int i = 0; i < 4; ++i)
        af[i] = *reinterpret_cast<const bf16x8*>(
            &As[(wm + i * 16 + m16) * GLDA + ks + quad * 8]);
#pragma unroll
      for (int j = 0; j < 4; ++j)
        bfr[j] = *reinterpret_cast<const bf16x8*>(
            &Bs[(wn + j * 16 + m16) * GLDA + ks + quad * 8]);
#pragma unroll
      for (int i = 0; i < 4; ++i)
#pragma unroll
        for (int j = 0; j < 4; ++j)
          acc[i][j] = __builtin_amdgcn_mfma_f32_16x16x32_bf16(
              af[i], bfr[j], acc[i][j], 0, 0, 0);
    }
    __syncthreads();
  }
  // epilogue: C/D layout col=lane&15, row=quad*4+reg  [m89/m91 verified]
#pragma unroll
  for (int i = 0; i < 4; ++i) {
    const int rbase = bm + wm + i * 16 + quad * 4;
#pragma unroll
    for (int j = 0; j < 4; ++j) {
      const int col = bn + wn + j * 16 + m16;
      const float bv = bias[col];
#pragma unroll
      for (int r = 0; r < 4; ++r)
        C[(size_t)(rbase + r) * N + col] = acc[i][j][r] + bv;
    }
  }
}

// ---------------------------------------------------------------------------
// RoPE, interleaved pairs, in-place on Q and K. d=128, half=64 hard-coded.
// ---------------------------------------------------------------------------
__global__ void rope_kernel(float* __restrict__ Q, float* __restrict__ K,
                            int total, int S, int H) {
  int idx = blockIdx.x * blockDim.x + threadIdx.x;  // over B*S*(H/2)
  if (idx >= total) return;
  const int pairs = H >> 1;
  const int row = idx / pairs;           // b*S + s
  const int p = idx - row * pairs;
  const int h = p >> 6;                  // head
  const int i = p & 63;                  // freq index
  const int s = row % S;
  const float inv = 1.0f / powf(10000.0f, (float)i * (1.0f / 64.0f));
  const float ang = (float)s * inv;
  const float c = cosf(ang), sn = sinf(ang);
  const size_t off = (size_t)row * H + h * 128 + 2 * i;
  float2 q = *reinterpret_cast<float2*>(Q + off);
  float2 k = *reinterpret_cast<float2*>(K + off);
  float2 qo, ko;
  qo.x = q.x * c - q.y * sn;  qo.y = q.y * c + q.x * sn;
  ko.x = k.x * c - k.y * sn;  ko.y = k.y * c + k.x * sn;
  *reinterpret_cast<float2*>(Q + off) = qo;
  *reinterpret_cast<float2*>(K + off) = ko;
}

// ---------------------------------------------------------------------------
// Flash-style causal attention. Block = 32 q-rows of one (b,h).
// Q tile fp32 in LDS; K/V tiles (64 rows) bf16 in LDS; online softmax fp32.
// Writes O in-place over Q (block reads its own Q rows into LDS first).
// ---------------------------------------------------------------------------
constexpr int ATQ = 32, ATK = 64, ADH = 128;
constexpr int AQS = 132;  // Q lds stride (floats)  -> 16B aligned rows
constexpr int AKS = 140;  // K/V lds stride (ushorts) -> 8B aligned, 16 bank starts
constexpr int ASS = 66;   // scores stride (floats)

__global__ __launch_bounds__(256) void attn_kernel(
    const float* __restrict__ Qg, const float* __restrict__ Kg,
    const float* __restrict__ Vg, float* __restrict__ Og,
    int S, int H, int nh) {
  __shared__ float Qs[ATQ * AQS];
  __shared__ unsigned short Ks[ATK * AKS];
  __shared__ unsigned short Vs[ATK * AKS];
  __shared__ float Ss[ATQ * ASS];
  __shared__ float alpha_s[ATQ];
  __shared__ float l_s[ATQ];

  const int t = threadIdx.x;
  const int lane = t & 63;
  const int wave = t >> 6;

  const int nqt = S / ATQ;
  const int q_t = blockIdx.x % nqt;
  const int bh = blockIdx.x / nqt;
  const int h = bh % nh;
  const int b = bh / nh;
  const int q0 = q_t * ATQ;

  const float* Qbase = Qg + ((size_t)b * S) * H + (size_t)h * ADH;
  const float* Kbase = Kg + ((size_t)b * S) * H + (size_t)h * ADH;
  const float* Vbase = Vg + ((size_t)b * S) * H + (size_t)h * ADH;
  float* Obase = Og + ((size_t)b * S) * H + (size_t)h * ADH;

  // stage Q tile: 32 x 128 floats
  {
    const int c4 = (t & 31) * 4;
    const int r0 = t >> 5;
#pragma unroll
    for (int it = 0; it < 4; ++it) {
      const int row = r0 + it * 8;
      *reinterpret_cast<float4*>(&Qs[row * AQS + c4]) =
          *reinterpret_cast<const float4*>(Qbase + (size_t)(q0 + row) * H + c4);
    }
  }

  // PV ownership: thread t -> q=t>>3, dim chunks {4*pc + 32*j4 .. +3}
  const int pq = t >> 3;
  const int pc = t & 7;
  float accv[4][4];
#pragma unroll
  for (int a = 0; a < 4; ++a)
#pragma unroll
    for (int e = 0; e < 4; ++e) accv[a][e] = 0.f;

  float m_run = -INFINITY, l_run = 0.f;  // live in threads t<32 (q=t)

  const int ntile = (q0 + ATQ + ATK - 1) / ATK;
  const float scale = 0.08838834764831845f;  // 1/sqrt(128)

  for (int tile = 0; tile < ntile; ++tile) {
    const int k0 = tile * ATK;
    __syncthreads();  // protect Ks/Vs/Ss from previous iteration readers
    // stage K/V tiles (fp32 -> bf16)
    {
      const int c4 = (t & 31) * 4;
      const int r0 = t >> 5;
#pragma unroll
      for (int it = 0; it < 8; ++it) {
        const int row = r0 + it * 8;
        const float4 kv = *reinterpret_cast<const float4*>(
            Kbase + (size_t)(k0 + row) * H + c4);
        const float4 vv = *reinterpret_cast<const float4*>(
            Vbase + (size_t)(k0 + row) * H + c4);
        ushort4 kb, vb;
        kb.x = f32_to_bf16(kv.x); kb.y = f32_to_bf16(kv.y);
        kb.z = f32_to_bf16(kv.z); kb.w = f32_to_bf16(kv.w);
        vb.x = f32_to_bf16(vv.x); vb.y = f32_to_bf16(vv.y);
        vb.z = f32_to_bf16(vv.z); vb.w = f32_to_bf16(vv.w);
        *reinterpret_cast<ushort4*>(&Ks[row * AKS + c4]) = kb;
        *reinterpret_cast<ushort4*>(&Vs[row * AKS + c4]) = vb;
      }
    }
    __syncthreads();
    // scores: wave w handles q rows [8w, 8w+8), lane = local k
    {
      float sreg[8];
#pragma unroll
      for (int qq = 0; qq < 8; ++qq) sreg[qq] = 0.f;
#pragma unroll
      for (int dc = 0; dc < 4; ++dc) {
        float kc[32];  // K row chunk cached in registers, reused across 8 q's
#pragma unroll
        for (int i2 = 0; i2 < 8; ++i2) {
          const ushort4 kb = *reinterpret_cast<const ushort4*>(
              &Ks[lane * AKS + dc * 32 + i2 * 4]);
          kc[i2 * 4 + 0] = bf16_to_f32(kb.x);
          kc[i2 * 4 + 1] = bf16_to_f32(kb.y);
          kc[i2 * 4 + 2] = bf16_to_f32(kb.z);
          kc[i2 * 4 + 3] = bf16_to_f32(kb.w);
        }
#pragma unroll
        for (int qq = 0; qq < 8; ++qq) {
          const float* qrow = &Qs[(wave * 8 + qq) * AQS + dc * 32];
          float s = 0.f;
#pragma unroll
          for (int i2 = 0; i2 < 8; ++i2) {
            const float4 qv = *reinterpret_cast<const float4*>(qrow + i2 * 4);
            s += qv.x * kc[i2 * 4] + qv.y * kc[i2 * 4 + 1] +
                 qv.z * kc[i2 * 4 + 2] + qv.w * kc[i2 * 4 + 3];
          }
          sreg[qq] += s;
        }
      }
      const int kg = k0 + lane;
#pragma unroll
      for (int qq = 0; qq < 8; ++qq) {
        const int qg = q0 + wave * 8 + qq;
        float sv = sreg[qq] * scale;
        if (kg > qg) sv = -INFINITY;  // causal mask
        Ss[(wave * 8 + qq) * ASS + lane] = sv;
      }
    }
    __syncthreads();
    // online softmax update: thread t<32 owns q=t
    if (t < ATQ) {
      float tmax = -INFINITY;
#pragma unroll 8
      for (int k = 0; k < ATK; ++k) tmax = fmaxf(tmax, Ss[t * ASS + k]);
      const float mnew = fmaxf(m_run, tmax);
      const float al = __expf(m_run - mnew);  // first tile: exp(-inf)=0
      float psum = 0.f;
#pragma unroll 8
      for (int k = 0; k < ATK; ++k) {
        const float pp = __expf(Ss[t * ASS + k] - mnew);  // masked -> 0
        Ss[t * ASS + k] = pp;
        psum += pp;
      }
      l_run = l_run * al + psum;
      m_run = mnew;
      alpha_s[t] = al;
      l_s[t] = l_run;
    }
    __syncthreads();
    // PV accumulate
    {
      const float al = alpha_s[pq];
#pragma unroll
      for (int a = 0; a < 4; ++a)
#pragma unroll
        for (int e = 0; e < 4; ++e) accv[a][e] *= al;
#pragma unroll 4
      for (int k = 0; k < ATK; ++k) {
        const float pp = Ss[pq * ASS + k];
#pragma unroll
        for (int j4 = 0; j4 < 4; ++j4) {
          const ushort4 vb = *reinterpret_cast<const ushort4*>(
              &Vs[k * AKS + pc * 4 + j4 * 32]);
          accv[j4][0] += pp * bf16_to_f32(vb.x);
          accv[j4][1] += pp * bf16_to_f32(vb.y);
          accv[j4][2] += pp * bf16_to_f32(vb.z);
          accv[j4][3] += pp * bf16_to_f32(vb.w);
        }
      }
    }
  }
  // epilogue: O = acc / l   (writes over this block's own Q rows only)
  {
    const float linv = 1.0f / l_s[pq];
    float* orow = Obase + (size_t)(q0 + pq) * H;
#pragma unroll
    for (int j4 = 0; j4 < 4; ++j4) {
      float4 o;
      o.x = accv[j4][0] * linv; o.y = accv[j4][1] * linv;
      o.z = accv[j4][2] * linv; o.w = accv[j4][3] * linv;
      *reinterpret_cast<float4*>(orow + pc * 4 + j4 * 32) = o;
    }
  }
}

// ---------------------------------------------------------------------------
// Launch
// ---------------------------------------------------------------------------
extern "C" void kernel_launch(void* const* d_in, const int* in_sizes, int n_in,
                              void* d_out, int out_size, void* d_ws,
                              size_t ws_size, hipStream_t stream) {
  const float* x  = (const float*)d_in[0];
  const float* Wq = (const float*)d_in[1];
  const float* bq = (const float*)d_in[2];
  const float* Wk = (const float*)d_in[3];
  const float* bk = (const float*)d_in[4];
  const float* Wv = (const float*)d_in[5];
  const float* bv = (const float*)d_in[6];
  const float* Wo = (const float*)d_in[7];
  const float* bo = (const float*)d_in[8];
  float* out = (float*)d_out;

  const int B = 2, S = 2048, H = 2048, nh = 16;
  const int M = B * S;  // 4096

  // workspace layout (151 MB total)
  unsigned short* Wqb = (unsigned short*)d_ws;
  unsigned short* Wkb = Wqb + (size_t)H * H;
  unsigned short* Wvb = Wkb + (size_t)H * H;
  unsigned short* Wob = Wvb + (size_t)H * H;
  unsigned short* xb  = Wob + (size_t)H * H;
  float* Q = (float*)(xb + (size_t)M * H);
  float* K = Q + (size_t)M * H;
  float* V = K + (size_t)M * H;
  float* O = Q;              // attention output in-place over Q
  unsigned short* Ob = xb;   // bf16 attention output over xb

  const int cast_w4 = H * H / 4;  // 1,048,576
  const int cast_x4 = M * H / 4;  // 2,097,152

  hipLaunchKernelGGL(cast_kernel, dim3(cast_x4 / 256), dim3(256), 0, stream,
                     x, xb, cast_x4);
  hipLaunchKernelGGL(cast_kernel, dim3(cast_w4 / 256), dim3(256), 0, stream,
                     Wq, Wqb, cast_w4);
  hipLaunchKernelGGL(cast_kernel, dim3(cast_w4 / 256), dim3(256), 0, stream,
                     Wk, Wkb, cast_w4);
  hipLaunchKernelGGL(cast_kernel, dim3(cast_w4 / 256), dim3(256), 0, stream,
                     Wv, Wvb, cast_w4);
  hipLaunchKernelGGL(cast_kernel, dim3(cast_w4 / 256), dim3(256), 0, stream,
                     Wo, Wob, cast_w4);

  dim3 ggrid(H / GT_N, M / GT_M);  // (16, 32)
  hipLaunchKernelGGL(gemm_bt_bias, ggrid, dim3(256), 0, stream,
                     xb, Wqb, bq, Q, M, H, H);
  hipLaunchKernelGGL(gemm_bt_bias, ggrid, dim3(256), 0, stream,
                     xb, Wkb, bk, K, M, H, H);
  hipLaunchKernelGGL(gemm_bt_bias, ggrid, dim3(256), 0, stream,
                     xb, Wvb, bv, V, M, H, H);

  const int rope_total = M * (H / 2);
  hipLaunchKernelGGL(rope_kernel, dim3(rope_total / 256), dim3(256), 0, stream,
                     Q, K, rope_total, S, H);

  hipLaunchKernelGGL(attn_kernel, dim3(B * nh * (S / ATQ)), dim3(256), 0,
                     stream, Q, K, V, O, S, H, nh);

  hipLaunchKernelGGL(cast_kernel, dim3(cast_x4 / 256), dim3(256), 0, stream,
                     O, Ob, cast_x4);

  hipLaunchKernelGGL(gemm_bt_bias, ggrid, dim3(256), 0, stream,
                     Ob, Wob, bo, out, M, H, H);
}

// Round 2
// 461.282 us; speedup vs baseline: 4.9582x; 4.9582x over previous
//
#include <hip/hip_runtime.h>
#include <math.h>

// ---------------------------------------------------------------------------
// Types / helpers
// ---------------------------------------------------------------------------
typedef __bf16 bf16x8 __attribute__((ext_vector_type(8)));
typedef float floatx4 __attribute__((ext_vector_type(4)));

__device__ __forceinline__ unsigned short f32_to_bf16(float f) {
  unsigned int u = __float_as_uint(f);
  u = u + 0x7FFFu + ((u >> 16) & 1u);   // RNE; inputs finite
  return (unsigned short)(u >> 16);
}
__device__ __forceinline__ float bf16_to_f32(unsigned short s) {
  return __uint_as_float(((unsigned int)s) << 16);
}

// ---------------------------------------------------------------------------
// fp32 -> bf16 cast (vectorized float4 -> ushort4)
// ---------------------------------------------------------------------------
__global__ void cast_kernel(const float* __restrict__ in,
                            unsigned short* __restrict__ out, int n4) {
  int i = blockIdx.x * blockDim.x + threadIdx.x;
  if (i >= n4) return;
  const float4 v = reinterpret_cast<const float4*>(in)[i];
  ushort4 o;
  o.x = f32_to_bf16(v.x); o.y = f32_to_bf16(v.y);
  o.z = f32_to_bf16(v.z); o.w = f32_to_bf16(v.w);
  reinterpret_cast<ushort4*>(out)[i] = o;
}

// ---------------------------------------------------------------------------
// GEMM: C[m][n] = sum_k A[m][k]*B[n][k] + bias[n]   (unchanged from round 0)
// ---------------------------------------------------------------------------
constexpr int GT_M = 128, GT_N = 128, GT_K = 64;
constexpr int GLDA = GT_K + 8;  // 72 elements

__global__ __launch_bounds__(256) void gemm_bt_bias(
    const unsigned short* __restrict__ A, const unsigned short* __restrict__ B,
    const float* __restrict__ bias, float* __restrict__ C,
    int M, int N, int K) {
  __shared__ unsigned short As[GT_M * GLDA];
  __shared__ unsigned short Bs[GT_N * GLDA];
  const int t = threadIdx.x;
  const int lane = t & 63;
  const int wave = t >> 6;
  const int bm = blockIdx.y * GT_M;
  const int bn = blockIdx.x * GT_N;
  const int wm = (wave & 1) * 64;
  const int wn = (wave >> 1) * 64;
  const int m16 = lane & 15;
  const int quad = lane >> 4;

  floatx4 acc[4][4];
#pragma unroll
  for (int i = 0; i < 4; ++i)
#pragma unroll
    for (int j = 0; j < 4; ++j) acc[i][j] = floatx4{0.f, 0.f, 0.f, 0.f};

  const int row0 = t >> 3;
  const int col8 = (t & 7) * 8;

  for (int k0 = 0; k0 < K; k0 += GT_K) {
    const unsigned short* Ag = A + (size_t)(bm + row0) * K + k0 + col8;
    const unsigned short* Bg = B + (size_t)(bn + row0) * K + k0 + col8;
#pragma unroll
    for (int it = 0; it < 4; ++it) {
      *reinterpret_cast<uint4*>(&As[(row0 + it * 32) * GLDA + col8]) =
          *reinterpret_cast<const uint4*>(Ag + (size_t)it * 32 * K);
      *reinterpret_cast<uint4*>(&Bs[(row0 + it * 32) * GLDA + col8]) =
          *reinterpret_cast<const uint4*>(Bg + (size_t)it * 32 * K);
    }
    __syncthreads();
#pragma unroll
    for (int ks = 0; ks < GT_K; ks += 32) {
      bf16x8 af[4], bfr[4];
#pragma unroll
      for (int i = 0; i < 4; ++i)
        af[i] = *reinterpret_cast<const bf16x8*>(
            &As[(wm + i * 16 + m16) * GLDA + ks + quad * 8]);
#pragma unroll
      for (int j = 0; j < 4; ++j)
        bfr[j] = *reinterpret_cast<const bf16x8*>(
            &Bs[(wn + j * 16 + m16) * GLDA + ks + quad * 8]);
#pragma unroll
      for (int i = 0; i < 4; ++i)
#pragma unroll
        for (int j = 0; j < 4; ++j)
          acc[i][j] = __builtin_amdgcn_mfma_f32_16x16x32_bf16(
              af[i], bfr[j], acc[i][j], 0, 0, 0);
    }
    __syncthreads();
  }
#pragma unroll
  for (int i = 0; i < 4; ++i) {
    const int rbase = bm + wm + i * 16 + quad * 4;
#pragma unroll
    for (int j = 0; j < 4; ++j) {
      const int col = bn + wn + j * 16 + m16;
      const float bv = bias[col];
#pragma unroll
      for (int r = 0; r < 4; ++r)
        C[(size_t)(rbase + r) * N + col] = acc[i][j][r] + bv;
    }
  }
}

// ---------------------------------------------------------------------------
// RoPE -> bf16. Q pre-scaled by (1/sqrt(128))*log2(e) so attention logits are
// base-2 and softmax can use raw exp2 with no max subtraction.
// ---------------------------------------------------------------------------
__global__ void rope_bf16_kernel(const float* __restrict__ Q,
                                 const float* __restrict__ K,
                                 unsigned int* __restrict__ Qb,
                                 unsigned int* __restrict__ Kb,
                                 int total, int S, int H, float qscale) {
  int idx = blockIdx.x * blockDim.x + threadIdx.x;  // over M*(H/2)
  if (idx >= total) return;
  const int pairs = H >> 1;
  const int row = idx / pairs;
  const int p = idx - row * pairs;
  const int i = p & 63;                 // freq index within head
  const int s = row & (S - 1);          // S power of 2
  const float inv = powf(10000.0f, -(float)i * (1.0f / 64.0f));
  const float ang = (float)s * inv;
  const float c = cosf(ang), sn = sinf(ang);
  const size_t off = (size_t)row * pairs + p;  // float2 / uint index
  const float2 q = reinterpret_cast<const float2*>(Q)[off];
  const float2 k = reinterpret_cast<const float2*>(K)[off];
  const float qx = (q.x * c - q.y * sn) * qscale;
  const float qy = (q.y * c + q.x * sn) * qscale;
  const float kx = k.x * c - k.y * sn;
  const float ky = k.y * c + k.x * sn;
  Qb[off] = (unsigned)f32_to_bf16(qx) | ((unsigned)f32_to_bf16(qy) << 16);
  Kb[off] = (unsigned)f32_to_bf16(kx) | ((unsigned)f32_to_bf16(ky) << 16);
}

// ---------------------------------------------------------------------------
// V fp32 [b][s][h*128+d]  ->  Vt bf16 [(b*nh+h)*128+d][s]   (LDS transpose)
// ---------------------------------------------------------------------------
__global__ __launch_bounds__(256) void vtrans_kernel(
    const float* __restrict__ V, unsigned short* __restrict__ Vtb,
    int S, int H, int nh) {
  __shared__ float T[32 * 132];
  const int t = threadIdx.x;
  const int s0 = blockIdx.x * 32;
  const int bh = blockIdx.y;
  const int h = bh & 15, b = bh >> 4;
  const float* base = V + ((size_t)(b * S + s0)) * H + h * 128;
  {
    const int sr = t >> 3, c0 = (t & 7) * 16;
#pragma unroll
    for (int ii = 0; ii < 4; ++ii)
      *reinterpret_cast<float4*>(&T[sr * 132 + c0 + ii * 4]) =
          *reinterpret_cast<const float4*>(base + (size_t)sr * H + c0 + ii * 4);
  }
  __syncthreads();
  {
    const int d = t >> 1, half = t & 1;
    unsigned short tmp[16];
#pragma unroll
    for (int k = 0; k < 16; ++k)
      tmp[k] = f32_to_bf16(T[(half * 16 + k) * 132 + d]);
    unsigned short* g = Vtb + ((size_t)bh * 128 + d) * S + s0 + half * 16;
    *reinterpret_cast<uint4*>(g) = *reinterpret_cast<uint4*>(&tmp[0]);
    *reinterpret_cast<uint4*>(g + 8) = *reinterpret_cast<uint4*>(&tmp[8]);
  }
}

// ---------------------------------------------------------------------------
// MFMA flash attention (causal). Block = 128 q rows of one (b,h); 4 waves,
// each wave 32 q rows (2 row-groups of 16). K-tile = 64. Q frags persistent
// in registers. No-max softmax: logits pre-scaled to log2 domain, p=exp2(s),
// alpha==1, l accumulated lane-locally, reduced once at the end.
// P goes C-layout -> LDS -> A-layout (guide-verified transform).
// O written directly as bf16 [b][s][h*128+d].
// ---------------------------------------------------------------------------
constexpr int F_BQ = 128, F_BK = 64, F_DH = 128;
constexpr int KS_STR = 136;  // 64 rows x (128+8)
constexpr int VS_STR = 72;   // 128 rows x (64+8)
constexpr int PS_STR = 72;   // 128 rows x (64+8)

__global__ __launch_bounds__(256, 2) void fattn_kernel(
    const unsigned short* __restrict__ Qb, const unsigned short* __restrict__ Kb,
    const unsigned short* __restrict__ Vtb, unsigned short* __restrict__ Ob,
    int S, int H, int nh) {
  __shared__ unsigned short Ks[F_BK * KS_STR];   // 17408 B
  __shared__ unsigned short Vts[F_DH * VS_STR];  // 18432 B
  __shared__ unsigned short Ps[F_BQ * PS_STR];   // 18432 B

  const int t = threadIdx.x;
  const int lane = t & 63;
  const int w = t >> 6;
  const int l15 = lane & 15;
  const int quad = lane >> 4;

  // load-balance remap: pair heavy diagonal tile qt with light 15-qt
  const int i = blockIdx.x;
  const int bh = i & 31;
  const int qt = (i < 256) ? (i >> 5) : (15 - ((i - 256) >> 5));
  const int h = bh & 15;
  const int b = bh >> 4;
  const int q0 = qt * F_BQ;

  const unsigned short* Qrow = Qb + ((size_t)(b * S + q0)) * H + h * F_DH;
  const unsigned short* Krow = Kb + ((size_t)b * S) * H + h * F_DH;
  const unsigned short* Vtrow = Vtb + ((size_t)bh * F_DH) * S;
  unsigned short* Orow = Ob + ((size_t)(b * S + q0)) * H + h * F_DH;

  // persistent Q a-frags: A[m=l15][k=ks*32+quad*8+..]
  bf16x8 aq[2][4];
#pragma unroll
  for (int qg = 0; qg < 2; ++qg)
#pragma unroll
    for (int ks = 0; ks < 4; ++ks)
      aq[qg][ks] = *reinterpret_cast<const bf16x8*>(
          Qrow + (size_t)(w * 32 + qg * 16 + l15) * H + ks * 32 + quad * 8);

  floatx4 oacc[2][8];
#pragma unroll
  for (int qg = 0; qg < 2; ++qg)
#pragma unroll
    for (int dj = 0; dj < 8; ++dj) oacc[qg][dj] = floatx4{0.f, 0.f, 0.f, 0.f};
  float lpart[2][4] = {{0.f, 0.f, 0.f, 0.f}, {0.f, 0.f, 0.f, 0.f}};
  int qrow[2][4];
#pragma unroll
  for (int qg = 0; qg < 2; ++qg)
#pragma unroll
    for (int r = 0; r < 4; ++r)
      qrow[qg][r] = q0 + w * 32 + qg * 16 + quad * 4 + r;

  const int ntile = q0 / F_BK + 2;
  for (int tile = 0; tile < ntile; ++tile) {
    const int k0 = tile * F_BK;
    __syncthreads();  // Ks/Vts readers from previous tile done
    // stage K tile: 64 x 128 bf16
    {
      const int kt = t >> 2, c0 = (t & 3) * 32;
      const unsigned short* g = Krow + (size_t)(k0 + kt) * H + c0;
#pragma unroll
      for (int ii = 0; ii < 4; ++ii)
        *reinterpret_cast<uint4*>(&Ks[kt * KS_STR + c0 + ii * 8]) =
            *reinterpret_cast<const uint4*>(g + ii * 8);
    }
    // stage Vt tile: 128 d x 64 kt bf16
    {
      const int d = t >> 1, c0 = (t & 1) * 32;
      const unsigned short* g = Vtrow + (size_t)d * S + k0 + c0;
#pragma unroll
      for (int ii = 0; ii < 4; ++ii)
        *reinterpret_cast<uint4*>(&Vts[d * VS_STR + c0 + ii * 8]) =
            *reinterpret_cast<const uint4*>(g + ii * 8);
    }
    __syncthreads();

    // S = Q.K^T : D[m=q][n=kt], k=d
    floatx4 sacc[2][4];
#pragma unroll
    for (int qg = 0; qg < 2; ++qg)
#pragma unroll
      for (int j = 0; j < 4; ++j) sacc[qg][j] = floatx4{0.f, 0.f, 0.f, 0.f};
#pragma unroll
    for (int j = 0; j < 4; ++j) {
      bf16x8 bk[4];
#pragma unroll
      for (int ks = 0; ks < 4; ++ks)
        bk[ks] = *reinterpret_cast<const bf16x8*>(
            &Ks[(j * 16 + l15) * KS_STR + ks * 32 + quad * 8]);
#pragma unroll
      for (int qg = 0; qg < 2; ++qg)
#pragma unroll
        for (int ks = 0; ks < 4; ++ks)
          sacc[qg][j] = __builtin_amdgcn_mfma_f32_16x16x32_bf16(
              aq[qg][ks], bk[ks], sacc[qg][j], 0, 0, 0);
    }

    // mask + exp2 + lane-local l + write P (bf16) to LDS
#pragma unroll
    for (int qg = 0; qg < 2; ++qg)
#pragma unroll
      for (int j = 0; j < 4; ++j) {
        const int ktg = k0 + j * 16 + l15;
#pragma unroll
        for (int r = 0; r < 4; ++r) {
          const float p =
              (ktg <= qrow[qg][r]) ? exp2f(sacc[qg][j][r]) : 0.0f;
          lpart[qg][r] += p;
          Ps[(w * 32 + qg * 16 + quad * 4 + r) * PS_STR + j * 16 + l15] =
              f32_to_bf16(p);
        }
      }

    // O += P.V : D[m=q][n=d], k=kt   (Ps is wave-private: no barrier needed)
#pragma unroll
    for (int ks2 = 0; ks2 < 2; ++ks2) {
      bf16x8 ap[2];
#pragma unroll
      for (int qg = 0; qg < 2; ++qg)
        ap[qg] = *reinterpret_cast<const bf16x8*>(
            &Ps[(w * 32 + qg * 16 + l15) * PS_STR + ks2 * 32 + quad * 8]);
#pragma unroll
      for (int dj = 0; dj < 8; ++dj) {
        const bf16x8 bv = *reinterpret_cast<const bf16x8*>(
            &Vts[(dj * 16 + l15) * VS_STR + ks2 * 32 + quad * 8]);
#pragma unroll
        for (int qg = 0; qg < 2; ++qg)
          oacc[qg][dj] = __builtin_amdgcn_mfma_f32_16x16x32_bf16(
              ap[qg], bv, oacc[qg][dj], 0, 0, 0);
      }
    }
  }

  // final l reduction (once) + O write (bf16)
#pragma unroll
  for (int qg = 0; qg < 2; ++qg)
#pragma unroll
    for (int r = 0; r < 4; ++r) {
      float l = lpart[qg][r];
      l += __shfl_xor(l, 1);
      l += __shfl_xor(l, 2);
      l += __shfl_xor(l, 4);
      l += __shfl_xor(l, 8);
      const float linv = 1.0f / l;
      unsigned short* orow =
          Orow + (size_t)(w * 32 + qg * 16 + quad * 4 + r) * H;
#pragma unroll
      for (int dj = 0; dj < 8; ++dj)
        orow[dj * 16 + l15] = f32_to_bf16(oacc[qg][dj][r] * linv);
    }
}

// ---------------------------------------------------------------------------
// Launch
// ---------------------------------------------------------------------------
extern "C" void kernel_launch(void* const* d_in, const int* in_sizes, int n_in,
                              void* d_out, int out_size, void* d_ws,
                              size_t ws_size, hipStream_t stream) {
  const float* x  = (const float*)d_in[0];
  const float* Wq = (const float*)d_in[1];
  const float* bq = (const float*)d_in[2];
  const float* Wk = (const float*)d_in[3];
  const float* bk = (const float*)d_in[4];
  const float* Wv = (const float*)d_in[5];
  const float* bv = (const float*)d_in[6];
  const float* Wo = (const float*)d_in[7];
  const float* bo = (const float*)d_in[8];
  float* out = (float*)d_out;

  const int B = 2, S = 2048, H = 2048, nh = 16;
  const int M = B * S;  // 4096

  // workspace layout (151.2 MB, with overlays)
  unsigned short* Wqb = (unsigned short*)d_ws;
  unsigned short* Wkb = Wqb + (size_t)H * H;
  unsigned short* Wvb = Wkb + (size_t)H * H;
  unsigned short* Wob = Wvb + (size_t)H * H;
  unsigned short* xb  = Wob + (size_t)H * H;
  float* Q = (float*)(xb + (size_t)M * H);
  float* K = Q + (size_t)M * H;
  float* V = K + (size_t)M * H;
  unsigned short* Vtb = xb;              // overlays xb (x dead after V GEMM)
  unsigned short* Qbb = (unsigned short*)V;      // overlays V (dead after vtrans)
  unsigned short* Kbb = Qbb + (size_t)M * H;
  unsigned short* Ob  = (unsigned short*)Q;      // overlays Q (dead after rope)

  const int cast_w4 = H * H / 4;
  const int cast_x4 = M * H / 4;

  hipLaunchKernelGGL(cast_kernel, dim3(cast_x4 / 256), dim3(256), 0, stream,
                     x, xb, cast_x4);
  hipLaunchKernelGGL(cast_kernel, dim3(cast_w4 / 256), dim3(256), 0, stream,
                     Wq, Wqb, cast_w4);
  hipLaunchKernelGGL(cast_kernel, dim3(cast_w4 / 256), dim3(256), 0, stream,
                     Wk, Wkb, cast_w4);
  hipLaunchKernelGGL(cast_kernel, dim3(cast_w4 / 256), dim3(256), 0, stream,
                     Wv, Wvb, cast_w4);
  hipLaunchKernelGGL(cast_kernel, dim3(cast_w4 / 256), dim3(256), 0, stream,
                     Wo, Wob, cast_w4);

  dim3 ggrid(H / GT_N, M / GT_M);  // (16, 32)
  hipLaunchKernelGGL(gemm_bt_bias, ggrid, dim3(256), 0, stream,
                     xb, Wqb, bq, Q, M, H, H);
  hipLaunchKernelGGL(gemm_bt_bias, ggrid, dim3(256), 0, stream,
                     xb, Wkb, bk, K, M, H, H);
  hipLaunchKernelGGL(gemm_bt_bias, ggrid, dim3(256), 0, stream,
                     xb, Wvb, bv, V, M, H, H);

  // V -> Vt bf16 (must precede rope: rope output overlays V)
  hipLaunchKernelGGL(vtrans_kernel, dim3(S / 32, B * nh), dim3(256), 0, stream,
                     V, Vtb, S, H, nh);

  // RoPE -> bf16; Q scaled by 1/sqrt(128)*log2(e) (log2-domain logits)
  const float qscale = 0.08838834764831845f * 1.4426950408889634f;
  const int rope_total = M * (H / 2);
  hipLaunchKernelGGL(rope_bf16_kernel, dim3(rope_total / 256), dim3(256), 0,
                     stream, Q, K, (unsigned int*)Qbb, (unsigned int*)Kbb,
                     rope_total, S, H, qscale);

  hipLaunchKernelGGL(fattn_kernel, dim3((S / F_BQ) * B * nh), dim3(256), 0,
                     stream, Qbb, Kbb, Vtb, Ob, S, H, nh);

  hipLaunchKernelGGL(gemm_bt_bias, ggrid, dim3(256), 0, stream,
                     Ob, Wob, bo, out, M, H, H);
}

// Round 3
// 447.974 us; speedup vs baseline: 5.1055x; 1.0297x over previous
//
#include <hip/hip_runtime.h>
#include <math.h>

// ---------------------------------------------------------------------------
// Types / helpers
// ---------------------------------------------------------------------------
typedef __bf16 bf16x8 __attribute__((ext_vector_type(8)));
typedef float floatx4 __attribute__((ext_vector_type(4)));

__device__ __forceinline__ unsigned short f32_to_bf16(float f) {
  unsigned int u = __float_as_uint(f);
  u = u + 0x7FFFu + ((u >> 16) & 1u);   // RNE; inputs finite
  return (unsigned short)(u >> 16);
}
__device__ __forceinline__ float bf16_to_f32(unsigned short s) {
  return __uint_as_float(((unsigned int)s) << 16);
}

// async global->LDS, 16B per lane. lds base must be wave-uniform; HW scatters
// lane i to ldsbase + i*16  [m97 pattern].
__device__ __forceinline__ void gld_lds16(const unsigned short* g,
                                          unsigned short* l) {
  __builtin_amdgcn_global_load_lds(
      (const __attribute__((address_space(1))) unsigned int*)g,
      (__attribute__((address_space(3))) unsigned int*)l, 16, 0, 0);
}

// ---------------------------------------------------------------------------
// fp32 -> bf16 cast (vectorized float4 -> ushort4)
// ---------------------------------------------------------------------------
__global__ void cast_kernel(const float* __restrict__ in,
                            unsigned short* __restrict__ out, int n4) {
  int i = blockIdx.x * blockDim.x + threadIdx.x;
  if (i >= n4) return;
  const float4 v = reinterpret_cast<const float4*>(in)[i];
  ushort4 o;
  o.x = f32_to_bf16(v.x); o.y = f32_to_bf16(v.y);
  o.z = f32_to_bf16(v.z); o.w = f32_to_bf16(v.w);
  reinterpret_cast<ushort4*>(out)[i] = o;
}

// ---------------------------------------------------------------------------
// RoPE cos/sin table: tab[s*64+i] = (cos, sin) of s / 10000^(i/64)
// ---------------------------------------------------------------------------
__global__ void rope_table_kernel(float2* __restrict__ tab, int total) {
  int idx = blockIdx.x * blockDim.x + threadIdx.x;
  if (idx >= total) return;
  const int s = idx >> 6, i = idx & 63;
  const float inv = powf(10000.0f, -(float)i * (1.0f / 64.0f));
  const float ang = (float)s * inv;
  tab[idx] = make_float2(cosf(ang), sinf(ang));
}

// ---------------------------------------------------------------------------
// Fused GEMM: C[m][n] = sum_k A[m][k]*B[n][k] + bias[n]
// A: MxK bf16 rm, B: NxK bf16 rm. 128x128 tile, BK=64, 4 waves, 4x4 16x16x32.
// Staging via global_load_lds width=16 into UNPADDED LDS (stride 64), with an
// XOR chunk swizzle applied on the GLOBAL address (lane permutation within a
// 128B segment -> coalescing preserved) so frag ds_read_b128s hit all 32
// banks uniformly (8 lanes/chunk = b128 minimum).
// EPI=0: fp32 out + bias.
// EPI=1: bias + RoPE (interleaved pairs, table lookup) -> bf16, scaled by scl.
// EPI=2: bias -> bf16 transposed Vt[(b*16 + col/128)*128 + col%128][s].
// ---------------------------------------------------------------------------
template <int EPI>
__global__ __launch_bounds__(256) void gemm_fused(
    const unsigned short* __restrict__ A, const unsigned short* __restrict__ B,
    const float* __restrict__ bias, float* __restrict__ Cf,
    unsigned short* __restrict__ Cb, const float2* __restrict__ tab,
    float scl, int M, int N, int K, int S) {
  __shared__ unsigned short As[128 * 64];
  __shared__ unsigned short Bs[128 * 64];
  const int t = threadIdx.x;
  const int lane = t & 63;
  const int w = t >> 6;
  const int bm = blockIdx.y * 128;
  const int bn = blockIdx.x * 128;
  const int wm = (w & 1) * 64;
  const int wn = (w >> 1) * 64;
  const int m16 = lane & 15;
  const int quad = lane >> 4;
  const int key = m16 & 7;

  // staging geometry: chunk ch = w*4+it covers LDS rows [ch*8, ch*8+8).
  // lane -> row ch*8 + lane/8, global col chunk (lane%8) ^ (lane/8)  (swizzle)
  const int lr = lane >> 3;
  const int lc = ((lane & 7) ^ lr) * 8;

  floatx4 acc[4][4];
#pragma unroll
  for (int i = 0; i < 4; ++i)
#pragma unroll
    for (int j = 0; j < 4; ++j) acc[i][j] = floatx4{0.f, 0.f, 0.f, 0.f};

  const unsigned short* Abase = A + (size_t)(bm + w * 32 + lr) * K + lc;
  const unsigned short* Bbase = B + (size_t)(bn + w * 32 + lr) * K + lc;

  for (int k0 = 0; k0 < K; k0 += 64) {
    __syncthreads();  // previous-iter readers done before overwrite
#pragma unroll
    for (int it = 0; it < 4; ++it) {
      gld_lds16(Abase + (size_t)it * 8 * K + k0, &As[(w * 4 + it) * 512]);
      gld_lds16(Bbase + (size_t)it * 8 * K + k0, &Bs[(w * 4 + it) * 512]);
    }
    __syncthreads();  // drains vmcnt(0): LDS data visible
#pragma unroll
    for (int ks = 0; ks < 64; ks += 32) {
      const int ck = ks >> 3;  // 0 or 4
      bf16x8 af[4], bfr[4];
#pragma unroll
      for (int i = 0; i < 4; ++i)
        af[i] = *reinterpret_cast<const bf16x8*>(
            &As[(wm + i * 16 + m16) * 64 + ((ck | quad) ^ key) * 8]);
#pragma unroll
      for (int j = 0; j < 4; ++j)
        bfr[j] = *reinterpret_cast<const bf16x8*>(
            &Bs[(wn + j * 16 + m16) * 64 + ((ck | quad) ^ key) * 8]);
#pragma unroll
      for (int i = 0; i < 4; ++i)
#pragma unroll
        for (int j = 0; j < 4; ++j)
          acc[i][j] = __builtin_amdgcn_mfma_f32_16x16x32_bf16(
              af[i], bfr[j], acc[i][j], 0, 0, 0);
    }
  }

  // epilogue: C/D layout col=lane&15, row=quad*4+reg  [m89/m91 verified]
#pragma unroll
  for (int i = 0; i < 4; ++i) {
    const int rbase = bm + wm + i * 16 + quad * 4;
#pragma unroll
    for (int j = 0; j < 4; ++j) {
      const int col = bn + wn + j * 16 + m16;
      const float bv = bias[col];
      if (EPI == 0) {
#pragma unroll
        for (int r = 0; r < 4; ++r)
          Cf[(size_t)(rbase + r) * N + col] = acc[i][j][r] + bv;
      } else if (EPI == 1) {
        const int pi = (col & 127) >> 1;
#pragma unroll
        for (int r = 0; r < 4; ++r) {
          const int row = rbase + r;
          const int s = row & (S - 1);
          const float v = acc[i][j][r] + bv;
          const float vp = __shfl_xor(v, 1);
          const float2 cs = tab[s * 64 + pi];
          // even lane holds x_even (v), partner x_odd (vp); computes both
          const float oe = (v * cs.x - vp * cs.y) * scl;
          const float oo = (vp * cs.x + v * cs.y) * scl;
          if ((m16 & 1) == 0) {
            const unsigned pk =
                (unsigned)f32_to_bf16(oe) | ((unsigned)f32_to_bf16(oo) << 16);
            *reinterpret_cast<unsigned*>(Cb + (size_t)row * N + col) = pk;
          }
        }
      } else {  // EPI == 2: transposed bf16 V
        const int b = rbase >> 11;           // S = 2048
        const int s = rbase & (S - 1);       // multiple of 4
        ushort4 pk;
        pk.x = f32_to_bf16(acc[i][j][0] + bv);
        pk.y = f32_to_bf16(acc[i][j][1] + bv);
        pk.z = f32_to_bf16(acc[i][j][2] + bv);
        pk.w = f32_to_bf16(acc[i][j][3] + bv);
        *reinterpret_cast<ushort4*>(
            Cb + ((size_t)((b << 11) + col)) * S + s) = pk;
      }
    }
  }
}

// ---------------------------------------------------------------------------
// MFMA flash attention (unchanged from round 1 — 97 us, next round's target)
// ---------------------------------------------------------------------------
constexpr int F_BQ = 128, F_BK = 64, F_DH = 128;
constexpr int KS_STR = 136;
constexpr int VS_STR = 72;
constexpr int PS_STR = 72;

__global__ __launch_bounds__(256, 2) void fattn_kernel(
    const unsigned short* __restrict__ Qb, const unsigned short* __restrict__ Kb,
    const unsigned short* __restrict__ Vtb, unsigned short* __restrict__ Ob,
    int S, int H, int nh) {
  __shared__ unsigned short Ks[F_BK * KS_STR];
  __shared__ unsigned short Vts[F_DH * VS_STR];
  __shared__ unsigned short Ps[F_BQ * PS_STR];

  const int t = threadIdx.x;
  const int lane = t & 63;
  const int w = t >> 6;
  const int l15 = lane & 15;
  const int quad = lane >> 4;

  const int i = blockIdx.x;
  const int bh = i & 31;
  const int qt = (i < 256) ? (i >> 5) : (15 - ((i - 256) >> 5));
  const int h = bh & 15;
  const int b = bh >> 4;
  const int q0 = qt * F_BQ;

  const unsigned short* Qrow = Qb + ((size_t)(b * S + q0)) * H + h * F_DH;
  const unsigned short* Krow = Kb + ((size_t)b * S) * H + h * F_DH;
  const unsigned short* Vtrow = Vtb + ((size_t)bh * F_DH) * S;
  unsigned short* Orow = Ob + ((size_t)(b * S + q0)) * H + h * F_DH;

  bf16x8 aq[2][4];
#pragma unroll
  for (int qg = 0; qg < 2; ++qg)
#pragma unroll
    for (int ks = 0; ks < 4; ++ks)
      aq[qg][ks] = *reinterpret_cast<const bf16x8*>(
          Qrow + (size_t)(w * 32 + qg * 16 + l15) * H + ks * 32 + quad * 8);

  floatx4 oacc[2][8];
#pragma unroll
  for (int qg = 0; qg < 2; ++qg)
#pragma unroll
    for (int dj = 0; dj < 8; ++dj) oacc[qg][dj] = floatx4{0.f, 0.f, 0.f, 0.f};
  float lpart[2][4] = {{0.f, 0.f, 0.f, 0.f}, {0.f, 0.f, 0.f, 0.f}};
  int qrow[2][4];
#pragma unroll
  for (int qg = 0; qg < 2; ++qg)
#pragma unroll
    for (int r = 0; r < 4; ++r)
      qrow[qg][r] = q0 + w * 32 + qg * 16 + quad * 4 + r;

  const int ntile = q0 / F_BK + 2;
  for (int tile = 0; tile < ntile; ++tile) {
    const int k0 = tile * F_BK;
    __syncthreads();
    {
      const int kt = t >> 2, c0 = (t & 3) * 32;
      const unsigned short* g = Krow + (size_t)(k0 + kt) * H + c0;
#pragma unroll
      for (int ii = 0; ii < 4; ++ii)
        *reinterpret_cast<uint4*>(&Ks[kt * KS_STR + c0 + ii * 8]) =
            *reinterpret_cast<const uint4*>(g + ii * 8);
    }
    {
      const int d = t >> 1, c0 = (t & 1) * 32;
      const unsigned short* g = Vtrow + (size_t)d * S + k0 + c0;
#pragma unroll
      for (int ii = 0; ii < 4; ++ii)
        *reinterpret_cast<uint4*>(&Vts[d * VS_STR + c0 + ii * 8]) =
            *reinterpret_cast<const uint4*>(g + ii * 8);
    }
    __syncthreads();

    floatx4 sacc[2][4];
#pragma unroll
    for (int qg = 0; qg < 2; ++qg)
#pragma unroll
      for (int j = 0; j < 4; ++j) sacc[qg][j] = floatx4{0.f, 0.f, 0.f, 0.f};
#pragma unroll
    for (int j = 0; j < 4; ++j) {
      bf16x8 bk[4];
#pragma unroll
      for (int ks = 0; ks < 4; ++ks)
        bk[ks] = *reinterpret_cast<const bf16x8*>(
            &Ks[(j * 16 + l15) * KS_STR + ks * 32 + quad * 8]);
#pragma unroll
      for (int qg = 0; qg < 2; ++qg)
#pragma unroll
        for (int ks = 0; ks < 4; ++ks)
          sacc[qg][j] = __builtin_amdgcn_mfma_f32_16x16x32_bf16(
              aq[qg][ks], bk[ks], sacc[qg][j], 0, 0, 0);
    }

#pragma unroll
    for (int qg = 0; qg < 2; ++qg)
#pragma unroll
      for (int j = 0; j < 4; ++j) {
        const int ktg = k0 + j * 16 + l15;
#pragma unroll
        for (int r = 0; r < 4; ++r) {
          const float p =
              (ktg <= qrow[qg][r]) ? exp2f(sacc[qg][j][r]) : 0.0f;
          lpart[qg][r] += p;
          Ps[(w * 32 + qg * 16 + quad * 4 + r) * PS_STR + j * 16 + l15] =
              f32_to_bf16(p);
        }
      }

#pragma unroll
    for (int ks2 = 0; ks2 < 2; ++ks2) {
      bf16x8 ap[2];
#pragma unroll
      for (int qg = 0; qg < 2; ++qg)
        ap[qg] = *reinterpret_cast<const bf16x8*>(
            &Ps[(w * 32 + qg * 16 + l15) * PS_STR + ks2 * 32 + quad * 8]);
#pragma unroll
      for (int dj = 0; dj < 8; ++dj) {
        const bf16x8 bv = *reinterpret_cast<const bf16x8*>(
            &Vts[(dj * 16 + l15) * VS_STR + ks2 * 32 + quad * 8]);
#pragma unroll
        for (int qg = 0; qg < 2; ++qg)
          oacc[qg][dj] = __builtin_amdgcn_mfma_f32_16x16x32_bf16(
              ap[qg], bv, oacc[qg][dj], 0, 0, 0);
      }
    }
  }

#pragma unroll
  for (int qg = 0; qg < 2; ++qg)
#pragma unroll
    for (int r = 0; r < 4; ++r) {
      float l = lpart[qg][r];
      l += __shfl_xor(l, 1);
      l += __shfl_xor(l, 2);
      l += __shfl_xor(l, 4);
      l += __shfl_xor(l, 8);
      const float linv = 1.0f / l;
      unsigned short* orow =
          Orow + (size_t)(w * 32 + qg * 16 + quad * 4 + r) * H;
#pragma unroll
      for (int dj = 0; dj < 8; ++dj)
        orow[dj * 16 + l15] = f32_to_bf16(oacc[qg][dj][r] * linv);
    }
}

// ---------------------------------------------------------------------------
// Launch
// ---------------------------------------------------------------------------
extern "C" void kernel_launch(void* const* d_in, const int* in_sizes, int n_in,
                              void* d_out, int out_size, void* d_ws,
                              size_t ws_size, hipStream_t stream) {
  const float* x  = (const float*)d_in[0];
  const float* Wq = (const float*)d_in[1];
  const float* bq = (const float*)d_in[2];
  const float* Wk = (const float*)d_in[3];
  const float* bk = (const float*)d_in[4];
  const float* Wv = (const float*)d_in[5];
  const float* bv = (const float*)d_in[6];
  const float* Wo = (const float*)d_in[7];
  const float* bo = (const float*)d_in[8];
  float* out = (float*)d_out;

  const int B = 2, S = 2048, H = 2048, nh = 16;
  const int M = B * S;  // 4096

  // workspace layout (~113 MB, no overlays)
  unsigned short* Wqb = (unsigned short*)d_ws;
  unsigned short* Wkb = Wqb + (size_t)H * H;
  unsigned short* Wvb = Wkb + (size_t)H * H;
  unsigned short* Wob = Wvb + (size_t)H * H;
  unsigned short* xb  = Wob + (size_t)H * H;
  unsigned short* Qbb = xb + (size_t)M * H;
  unsigned short* Kbb = Qbb + (size_t)M * H;
  unsigned short* Vtb = Kbb + (size_t)M * H;
  unsigned short* Ob  = Vtb + (size_t)M * H;
  float2* tab = (float2*)(Ob + (size_t)M * H);  // S*64 float2 = 1 MB

  const int cast_w4 = H * H / 4;
  const int cast_x4 = M * H / 4;
  const int tab_n = S * 64;

  rope_table_kernel<<<dim3(tab_n / 256), dim3(256), 0, stream>>>(tab, tab_n);
  cast_kernel<<<dim3(cast_x4 / 256), dim3(256), 0, stream>>>(x, xb, cast_x4);
  cast_kernel<<<dim3(cast_w4 / 256), dim3(256), 0, stream>>>(Wq, Wqb, cast_w4);
  cast_kernel<<<dim3(cast_w4 / 256), dim3(256), 0, stream>>>(Wk, Wkb, cast_w4);
  cast_kernel<<<dim3(cast_w4 / 256), dim3(256), 0, stream>>>(Wv, Wvb, cast_w4);
  cast_kernel<<<dim3(cast_w4 / 256), dim3(256), 0, stream>>>(Wo, Wob, cast_w4);

  dim3 ggrid(H / 128, M / 128);  // (16, 32)
  const float qscale = 0.08838834764831845f * 1.4426950408889634f;

  gemm_fused<1><<<ggrid, dim3(256), 0, stream>>>(
      xb, Wqb, bq, nullptr, Qbb, tab, qscale, M, H, H, S);
  gemm_fused<1><<<ggrid, dim3(256), 0, stream>>>(
      xb, Wkb, bk, nullptr, Kbb, tab, 1.0f, M, H, H, S);
  gemm_fused<2><<<ggrid, dim3(256), 0, stream>>>(
      xb, Wvb, bv, nullptr, Vtb, nullptr, 1.0f, M, H, H, S);

  fattn_kernel<<<dim3((S / F_BQ) * B * nh), dim3(256), 0, stream>>>(
      Qbb, Kbb, Vtb, Ob, S, H, nh);

  gemm_fused<0><<<ggrid, dim3(256), 0, stream>>>(
      Ob, Wob, bo, out, nullptr, nullptr, 1.0f, M, H, H, S);
}